// Round 1
// baseline (864.537 us; speedup 1.0000x reference)
//
#include <hip/hip_runtime.h>

namespace {

constexpr int kHW = 36864;         // 192*192
constexpr int kE = 256;
constexpr int kFocalElems = 7744 * 80;

__device__ __forceinline__ float wave_sum(float v) {
#pragma unroll
  for (int off = 32; off; off >>= 1) v += __shfl_xor(v, off, 64);
  return v;
}

// ---------------------------------------------------------------------------
// Main fused kernel: dynamic 1x1 conv (80 rows x E=256 dot products per pixel)
// + sigmoid + dice partial sums (a, b, c per row) accumulated into acc[0..479].
// One thread per pixel; grid = (HW/64, B).
// ---------------------------------------------------------------------------
__global__ __launch_bounds__(64) void solov2_main(
    const float* __restrict__ mask_out,
    const float* __restrict__ k0, const float* __restrict__ k1,
    const float* __restrict__ k2, const float* __restrict__ k3,
    const float* __restrict__ k4,
    const int* __restrict__ p0, const int* __restrict__ p1,
    const int* __restrict__ p2, const int* __restrict__ p3,
    const int* __restrict__ p4,
    const float* __restrict__ mask_targets,
    float* __restrict__ acc) {
  const int b = blockIdx.y;
  const int pix = blockIdx.x * 64 + threadIdx.x;
  const float* __restrict__ mo = mask_out + (size_t)b * kE * kHW + pix;

  const float* kb[5] = {k0, k1, k2, k3, k4};
  const int* pb[5] = {p0, p1, p2, p3, p4};
  const int bg2[5] = {b * 1600, b * 1296, b * 576, b * 256, b * 144};

  float pred[80];
#pragma unroll
  for (int i = 0; i < 80; ++i) pred[i] = 0.f;

  float ma[8], mb_[8];

#define LOADM(M, E0)                                                        \
  {                                                                         \
    _Pragma("unroll") for (int j = 0; j < 8; ++j)                           \
        M[j] = mo[(size_t)((E0) + j) * kHW];                                \
  }

#define KROWS(M, E0)                                                        \
  {                                                                         \
    _Pragma("unroll") for (int l = 0; l < 5; ++l) {                         \
      _Pragma("unroll") for (int p = 0; p < 16; ++p) {                      \
        const int pos = pb[l][b * 16 + p];                                  \
        const float* __restrict__ kr =                                      \
            kb[l] + (size_t)(bg2[l] + pos) * 256 + (E0);                    \
        _Pragma("unroll") for (int j = 0; j < 8; ++j)                       \
            pred[l * 16 + p] = fmaf(kr[j], M[j], pred[l * 16 + p]);         \
      }                                                                     \
    }                                                                       \
  }

  // Double-buffered e-loop: prefetch next 8 mask_out channels while doing
  // 640 FMAs on the current 8.
  LOADM(ma, 0);
  for (int e0 = 0; e0 < 256; e0 += 16) {
    LOADM(mb_, e0 + 8);
    KROWS(ma, e0);
    if (e0 + 16 < 256) LOADM(ma, e0 + 16);
    KROWS(mb_, e0 + 8);
  }
#undef LOADM
#undef KROWS

  // Dice epilogue. Pred row (level-major) r = l*B*P + b*P + p = 32l+16b+p
  // pairs with mask_targets flat row r (the reference's intentional
  // level-major / image-major mismatch collapses to "same flat row index").
#pragma unroll
  for (int l = 0; l < 5; ++l) {
#pragma unroll
    for (int p = 0; p < 16; ++p) {
      const int r = l * 32 + b * 16 + p;
      const float x = pred[l * 16 + p];
      const float mp = 1.f / (1.f + __expf(-x));
      const float mt = mask_targets[(size_t)r * kHW + pix];
      const float av = wave_sum(mp * mt);
      const float bv = wave_sum(mp * mp);
      const float cv = wave_sum(mt);  // mt is binary: mt*mt == mt
      if (threadIdx.x == 0) {
        unsafeAtomicAdd(&acc[r], av);
        unsafeAtomicAdd(&acc[160 + r], bv);
        unsafeAtomicAdd(&acc[320 + r], cv);
      }
    }
  }
}

// ---------------------------------------------------------------------------
// Focal loss over concatenated grid cells. N = 7744 cells x C = 80 classes.
// term = alpha_f * (1-pt)^2 * (-log(pt)), pt = p if c==t else 1-p, masked by
// t > -1. acc[480] += sum(term), acc[481] += npos.
// ---------------------------------------------------------------------------
__global__ __launch_bounds__(256) void focal_kernel(
    const float* __restrict__ c0, const float* __restrict__ c1,
    const float* __restrict__ c2, const float* __restrict__ c3,
    const float* __restrict__ c4,
    const int* __restrict__ t0, const int* __restrict__ t1,
    const int* __restrict__ t2, const int* __restrict__ t3,
    const int* __restrict__ t4,
    float* __restrict__ acc) {
  float term = 0.f, np = 0.f;
  for (int idx = blockIdx.x * 256 + threadIdx.x; idx < kFocalElems;
       idx += gridDim.x * 256) {
    const int n = idx / 80;       // cell index in concat order
    const int c = idx - n * 80;   // class
    int t;
    const float* crow;
    if (n < 3200) {
      t = t0[n]; crow = c0 + (size_t)n * 80;
    } else if (n < 5792) {
      const int o = n - 3200; t = t1[o]; crow = c1 + (size_t)o * 80;
    } else if (n < 6944) {
      const int o = n - 5792; t = t2[o]; crow = c2 + (size_t)o * 80;
    } else if (n < 7456) {
      const int o = n - 6944; t = t3[o]; crow = c3 + (size_t)o * 80;
    } else {
      const int o = n - 7456; t = t4[o]; crow = c4 + (size_t)o * 80;
    }
    if (t > -1) {
      float pv = crow[c];
      pv = fminf(fmaxf(pv, 1e-4f), 1.f - 1e-4f);
      const bool g = (c == t);
      const float af = g ? 0.25f : 0.75f;
      const float pt = g ? pv : 1.f - pv;
      const float om = 1.f - pt;
      term = fmaf(af * om * om, -__logf(pt), term);
      if (c == 0) np += 1.f;
    }
  }
  term = wave_sum(term);
  np = wave_sum(np);
  __shared__ float st[8];
  const int wid = threadIdx.x >> 6;
  if ((threadIdx.x & 63) == 0) {
    st[wid] = term;
    st[4 + wid] = np;
  }
  __syncthreads();
  if (threadIdx.x == 0) {
    unsafeAtomicAdd(&acc[480], st[0] + st[1] + st[2] + st[3]);
    unsafeAtomicAdd(&acc[481], st[4] + st[5] + st[6] + st[7]);
  }
}

__global__ void zero_kernel(float* __restrict__ acc) {
  const int i = blockIdx.x * 256 + threadIdx.x;
  if (i < 482) acc[i] = 0.f;
}

__global__ __launch_bounds__(64) void finalize_kernel(
    const float* __restrict__ acc, float* __restrict__ out) {
  const int tid = threadIdx.x;
  float s = 0.f;
#pragma unroll
  for (int rr = 0; rr < 3; ++rr) {
    const int r = tid + rr * 64;
    if (r < 160) {
      const float a = acc[r];
      const float bb = acc[160 + r];
      const float cc = acc[320 + r];
      s += 1.f - 2.f * a / (bb + cc + 1e-4f);
    }
  }
  s = wave_sum(s);
  if (tid == 0) {
    out[0] = 3.0f * (s / 160.f);          // MASK_W * mask_loss
    out[1] = acc[480] / acc[481];         // CLS_W * cls_loss
  }
}

}  // namespace

extern "C" void kernel_launch(void* const* d_in, const int* in_sizes, int n_in,
                              void* d_out, int out_size, void* d_ws,
                              size_t ws_size, hipStream_t stream) {
  const float* mask_out = (const float*)d_in[0];
  const float* k[5];
  const float* cc[5];
  const int* pp[5];
  const int* tt[5];
  for (int i = 0; i < 5; ++i) {
    k[i] = (const float*)d_in[1 + 4 * i];
    cc[i] = (const float*)d_in[2 + 4 * i];
    pp[i] = (const int*)d_in[3 + 4 * i];
    tt[i] = (const int*)d_in[4 + 4 * i];
  }
  const float* mt = (const float*)d_in[21];
  float* acc = (float*)d_ws;
  float* out = (float*)d_out;

  hipLaunchKernelGGL(zero_kernel, dim3(2), dim3(256), 0, stream, acc);
  hipLaunchKernelGGL(solov2_main, dim3(36864 / 64, 2), dim3(64), 0, stream,
                     mask_out, k[0], k[1], k[2], k[3], k[4], pp[0], pp[1],
                     pp[2], pp[3], pp[4], mt, acc);
  hipLaunchKernelGGL(focal_kernel, dim3(320), dim3(256), 0, stream, cc[0],
                     cc[1], cc[2], cc[3], cc[4], tt[0], tt[1], tt[2], tt[3],
                     tt[4], acc);
  hipLaunchKernelGGL(finalize_kernel, dim3(1), dim3(64), 0, stream, acc, out);
}

// Round 2
// 551.319 us; speedup vs baseline: 1.5681x; 1.5681x over previous
//
#include <hip/hip_runtime.h>

namespace {

constexpr int kHW = 36864;  // 192*192
constexpr int kFocalElems = 7744 * 80;

__device__ __forceinline__ float wave_sum(float v) {
#pragma unroll
  for (int off = 32; off; off >>= 1) v += __shfl_xor(v, off, 64);
  return v;
}

// ---------------------------------------------------------------------------
// Main fused kernel. Block = 256 threads; handles 512 pixels (2/thread) x
// 20 pred rows. Grid = (72 pixel-tiles, 4 row-groups, 2 batches).
// K rows staged in LDS once (20 KB); inner loop: broadcast ds_read_b128 of K,
// float2 mask_out loads, 40 fp32 accumulators per thread. Dice partials
// accumulated into acc[0..479] via per-wave atomics.
// ---------------------------------------------------------------------------
__global__ __launch_bounds__(256, 4) void solov2_main(
    const float* __restrict__ mask_out,
    const float* __restrict__ k0, const float* __restrict__ k1,
    const float* __restrict__ k2, const float* __restrict__ k3,
    const float* __restrict__ k4,
    const int* __restrict__ q0, const int* __restrict__ q1,
    const int* __restrict__ q2, const int* __restrict__ q3,
    const int* __restrict__ q4,
    const float* __restrict__ mask_targets,
    float* __restrict__ acc) {
  const int b = blockIdx.z;
  const int g = blockIdx.y;  // row group: rows [g*20, g*20+20)
  const int pixbase = blockIdx.x * 512 + threadIdx.x * 2;
  const float* __restrict__ mo = mask_out + (size_t)b * 256 * kHW + pixbase;

  const float* kb[5] = {k0, k1, k2, k3, k4};
  const int* pb[5] = {q0, q1, q2, q3, q4};
  const int bg2[5] = {b * 1600, b * 1296, b * 576, b * 256, b * 144};

  // --- stage this block's 20 kernel rows into LDS (row j loaded on iter j,
  // 256 channels by the 256 threads -> coalesced) ---
  __shared__ float klds[20][256];
#pragma unroll
  for (int j = 0; j < 20; ++j) {
    const int grow = g * 20 + j;
    const int l = grow >> 4, p = grow & 15;   // uniform (g is uniform)
    const int pos = pb[l][b * 16 + p];
    klds[j][threadIdx.x] =
        kb[l][(size_t)(bg2[l] + pos) * 256 + threadIdx.x];
  }
  __syncthreads();

  float pa[20], pc[20];
#pragma unroll
  for (int i = 0; i < 20; ++i) { pa[i] = 0.f; pc[i] = 0.f; }

  float2 ma[8], mb_[8];

#define LOADM(M, E0)                                                        \
  {                                                                         \
    _Pragma("unroll") for (int j = 0; j < 8; ++j)                           \
        M[j] = *(const float2*)&mo[(size_t)((E0) + j) * kHW];               \
  }

#define KROWS(M, E0)                                                        \
  {                                                                         \
    _Pragma("unroll") for (int rr = 0; rr < 20; ++rr) {                     \
      const float4 ka = *(const float4*)&klds[rr][(E0)];                    \
      const float4 kc = *(const float4*)&klds[rr][(E0) + 4];                \
      const float kk[8] = {ka.x, ka.y, ka.z, ka.w,                          \
                           kc.x, kc.y, kc.z, kc.w};                         \
      _Pragma("unroll") for (int j = 0; j < 8; ++j) {                       \
        pa[rr] = fmaf(kk[j], M[j].x, pa[rr]);                               \
        pc[rr] = fmaf(kk[j], M[j].y, pc[rr]);                               \
      }                                                                     \
    }                                                                       \
  }

  // Double-buffered e-loop: prefetch next 8 channels during 320 FMAs.
  LOADM(ma, 0);
  for (int e0 = 0; e0 < 256; e0 += 16) {
    LOADM(mb_, e0 + 8);
    KROWS(ma, e0);
    if (e0 + 16 < 256) LOADM(ma, e0 + 16);
    KROWS(mb_, e0 + 8);
  }
#undef LOADM
#undef KROWS

  // Dice epilogue. Global flat row r = l*32 + b*16 + p pairs with
  // mask_targets flat row r (reference's level-major/image-major mismatch
  // collapses to identical flat indexing).
  const int lane = threadIdx.x & 63;
#pragma unroll
  for (int rr = 0; rr < 20; ++rr) {
    const int grow = g * 20 + rr;
    const int l = grow >> 4, p = grow & 15;
    const int r = l * 32 + b * 16 + p;
    const float mp0 = 1.f / (1.f + __expf(-pa[rr]));
    const float mp1 = 1.f / (1.f + __expf(-pc[rr]));
    const float2 mt = *(const float2*)&mask_targets[(size_t)r * kHW + pixbase];
    const float av = wave_sum(fmaf(mp0, mt.x, mp1 * mt.y));
    const float bv = wave_sum(fmaf(mp0, mp0, mp1 * mp1));
    const float cv = wave_sum(mt.x + mt.y);  // binary targets: mt*mt == mt
    if (lane == 0) {
      unsafeAtomicAdd(&acc[r], av);
      unsafeAtomicAdd(&acc[160 + r], bv);
      unsafeAtomicAdd(&acc[320 + r], cv);
    }
  }
}

// ---------------------------------------------------------------------------
// Focal loss over concatenated grid cells. N = 7744 cells x C = 80 classes.
// ---------------------------------------------------------------------------
__global__ __launch_bounds__(256) void focal_kernel(
    const float* __restrict__ c0, const float* __restrict__ c1,
    const float* __restrict__ c2, const float* __restrict__ c3,
    const float* __restrict__ c4,
    const int* __restrict__ t0, const int* __restrict__ t1,
    const int* __restrict__ t2, const int* __restrict__ t3,
    const int* __restrict__ t4,
    float* __restrict__ acc) {
  float term = 0.f, np = 0.f;
  for (int idx = blockIdx.x * 256 + threadIdx.x; idx < kFocalElems;
       idx += gridDim.x * 256) {
    const int n = idx / 80;       // cell index in concat order
    const int c = idx - n * 80;   // class
    int t;
    const float* crow;
    if (n < 3200) {
      t = t0[n]; crow = c0 + (size_t)n * 80;
    } else if (n < 5792) {
      const int o = n - 3200; t = t1[o]; crow = c1 + (size_t)o * 80;
    } else if (n < 6944) {
      const int o = n - 5792; t = t2[o]; crow = c2 + (size_t)o * 80;
    } else if (n < 7456) {
      const int o = n - 6944; t = t3[o]; crow = c3 + (size_t)o * 80;
    } else {
      const int o = n - 7456; t = t4[o]; crow = c4 + (size_t)o * 80;
    }
    if (t > -1) {
      float pv = crow[c];
      pv = fminf(fmaxf(pv, 1e-4f), 1.f - 1e-4f);
      const bool gm = (c == t);
      const float af = gm ? 0.25f : 0.75f;
      const float pt = gm ? pv : 1.f - pv;
      const float om = 1.f - pt;
      term = fmaf(af * om * om, -__logf(pt), term);
      if (c == 0) np += 1.f;
    }
  }
  term = wave_sum(term);
  np = wave_sum(np);
  __shared__ float st[8];
  const int wid = threadIdx.x >> 6;
  if ((threadIdx.x & 63) == 0) {
    st[wid] = term;
    st[4 + wid] = np;
  }
  __syncthreads();
  if (threadIdx.x == 0) {
    unsafeAtomicAdd(&acc[480], st[0] + st[1] + st[2] + st[3]);
    unsafeAtomicAdd(&acc[481], st[4] + st[5] + st[6] + st[7]);
  }
}

__global__ void zero_kernel(float* __restrict__ acc) {
  const int i = blockIdx.x * 256 + threadIdx.x;
  if (i < 482) acc[i] = 0.f;
}

__global__ __launch_bounds__(64) void finalize_kernel(
    const float* __restrict__ acc, float* __restrict__ out) {
  const int tid = threadIdx.x;
  float s = 0.f;
#pragma unroll
  for (int rr = 0; rr < 3; ++rr) {
    const int r = tid + rr * 64;
    if (r < 160) {
      const float a = acc[r];
      const float bb = acc[160 + r];
      const float cc = acc[320 + r];
      s += 1.f - 2.f * a / (bb + cc + 1e-4f);
    }
  }
  s = wave_sum(s);
  if (tid == 0) {
    out[0] = 3.0f * (s / 160.f);          // MASK_W * mask_loss
    out[1] = acc[480] / acc[481];         // CLS_W * cls_loss
  }
}

}  // namespace

extern "C" void kernel_launch(void* const* d_in, const int* in_sizes, int n_in,
                              void* d_out, int out_size, void* d_ws,
                              size_t ws_size, hipStream_t stream) {
  const float* mask_out = (const float*)d_in[0];
  const float* k[5];
  const float* cc[5];
  const int* pp[5];
  const int* tt[5];
  for (int i = 0; i < 5; ++i) {
    k[i] = (const float*)d_in[1 + 4 * i];
    cc[i] = (const float*)d_in[2 + 4 * i];
    pp[i] = (const int*)d_in[3 + 4 * i];
    tt[i] = (const int*)d_in[4 + 4 * i];
  }
  const float* mt = (const float*)d_in[21];
  float* acc = (float*)d_ws;
  float* out = (float*)d_out;

  hipLaunchKernelGGL(zero_kernel, dim3(2), dim3(256), 0, stream, acc);
  hipLaunchKernelGGL(solov2_main, dim3(72, 4, 2), dim3(256), 0, stream,
                     mask_out, k[0], k[1], k[2], k[3], k[4], pp[0], pp[1],
                     pp[2], pp[3], pp[4], mt, acc);
  hipLaunchKernelGGL(focal_kernel, dim3(320), dim3(256), 0, stream, cc[0],
                     cc[1], cc[2], cc[3], cc[4], tt[0], tt[1], tt[2], tt[3],
                     tt[4], acc);
  hipLaunchKernelGGL(finalize_kernel, dim3(1), dim3(64), 0, stream, acc, out);
}

// Round 3
// 463.180 us; speedup vs baseline: 1.8665x; 1.1903x over previous
//
#include <hip/hip_runtime.h>

namespace {

constexpr int kHW = 36864;  // 192*192
constexpr int kFocalElems = 7744 * 80;

__device__ __forceinline__ float wave_sum(float v) {
#pragma unroll
  for (int off = 32; off; off >>= 1) v += __shfl_xor(v, off, 64);
  return v;
}

// ---------------------------------------------------------------------------
// Main fused kernel. Block = 256 threads; 256 pixels (1/thread) x 40 rows.
// Grid = (144 pixel-tiles, 2 row-groups, 2 batches) = 576 blocks.
// K rows staged in LDS once (40 KB); inner loop: broadcast ds_read_b128 of K,
// coalesced dword mask_out loads (double-buffered), 40 fp32 accumulators.
// Dice partials accumulated into acc[0..479] via per-wave atomics.
// ---------------------------------------------------------------------------
__global__ __launch_bounds__(256, 1) void solov2_main(
    const float* __restrict__ mask_out,
    const float* __restrict__ k0, const float* __restrict__ k1,
    const float* __restrict__ k2, const float* __restrict__ k3,
    const float* __restrict__ k4,
    const int* __restrict__ q0, const int* __restrict__ q1,
    const int* __restrict__ q2, const int* __restrict__ q3,
    const int* __restrict__ q4,
    const float* __restrict__ mask_targets,
    float* __restrict__ acc) {
  const int b = blockIdx.z;
  const int g = blockIdx.y;  // row group: rows [g*40, g*40+40)
  const int pix = blockIdx.x * 256 + threadIdx.x;
  const float* __restrict__ mo = mask_out + (size_t)b * 256 * kHW + pix;

  const float* kb[5] = {k0, k1, k2, k3, k4};
  const int* pb[5] = {q0, q1, q2, q3, q4};
  const int bg2[5] = {b * 1600, b * 1296, b * 576, b * 256, b * 144};

  // --- stage this block's 40 kernel rows into LDS (coalesced: 256 channels
  // by the 256 threads per row) ---
  __shared__ float klds[40][256];
#pragma unroll
  for (int j = 0; j < 40; ++j) {
    const int grow = g * 40 + j;
    const int l = grow >> 4, p = grow & 15;  // uniform per block
    const int pos = pb[l][b * 16 + p];
    klds[j][threadIdx.x] = kb[l][(size_t)(bg2[l] + pos) * 256 + threadIdx.x];
  }
  __syncthreads();

  float pa[40];
#pragma unroll
  for (int i = 0; i < 40; ++i) pa[i] = 0.f;

  float ma[8], mb_[8];

#define LOADM(M, E0)                                                        \
  {                                                                         \
    _Pragma("unroll") for (int j = 0; j < 8; ++j)                           \
        M[j] = mo[(size_t)((E0) + j) * kHW];                                \
  }

#define KROWS(M, E0)                                                        \
  {                                                                         \
    _Pragma("unroll") for (int rr = 0; rr < 40; ++rr) {                     \
      const float4 ka = *(const float4*)&klds[rr][(E0)];                    \
      const float4 kc = *(const float4*)&klds[rr][(E0) + 4];                \
      pa[rr] = fmaf(ka.x, M[0], pa[rr]);                                    \
      pa[rr] = fmaf(ka.y, M[1], pa[rr]);                                    \
      pa[rr] = fmaf(ka.z, M[2], pa[rr]);                                    \
      pa[rr] = fmaf(ka.w, M[3], pa[rr]);                                    \
      pa[rr] = fmaf(kc.x, M[4], pa[rr]);                                    \
      pa[rr] = fmaf(kc.y, M[5], pa[rr]);                                    \
      pa[rr] = fmaf(kc.z, M[6], pa[rr]);                                    \
      pa[rr] = fmaf(kc.w, M[7], pa[rr]);                                    \
    }                                                                       \
  }

  // Double-buffered e-loop: prefetch next 8 channels during 320 FMAs.
  LOADM(ma, 0);
  for (int e0 = 0; e0 < 256; e0 += 16) {
    LOADM(mb_, e0 + 8);
    KROWS(ma, e0);
    if (e0 + 16 < 256) LOADM(ma, e0 + 16);
    KROWS(mb_, e0 + 8);
  }
#undef LOADM
#undef KROWS

  // Dice epilogue. Global flat row r = l*32 + b*16 + p pairs with
  // mask_targets flat row r (reference's level-major/image-major pairing
  // collapses to identical flat indexing).
  const int lane = threadIdx.x & 63;
#pragma unroll
  for (int rr = 0; rr < 40; ++rr) {
    const int grow = g * 40 + rr;
    const int l = grow >> 4, p = grow & 15;
    const int r = l * 32 + b * 16 + p;
    const float mp = 1.f / (1.f + __expf(-pa[rr]));
    const float mt = mask_targets[(size_t)r * kHW + pix];
    const float av = wave_sum(mp * mt);
    const float bv = wave_sum(mp * mp);
    const float cv = wave_sum(mt);  // binary targets: mt*mt == mt
    if (lane == 0) {
      unsafeAtomicAdd(&acc[r], av);
      unsafeAtomicAdd(&acc[160 + r], bv);
      unsafeAtomicAdd(&acc[320 + r], cv);
    }
  }
}

// ---------------------------------------------------------------------------
// Focal loss over concatenated grid cells. N = 7744 cells x C = 80 classes.
// ---------------------------------------------------------------------------
__global__ __launch_bounds__(256) void focal_kernel(
    const float* __restrict__ c0, const float* __restrict__ c1,
    const float* __restrict__ c2, const float* __restrict__ c3,
    const float* __restrict__ c4,
    const int* __restrict__ t0, const int* __restrict__ t1,
    const int* __restrict__ t2, const int* __restrict__ t3,
    const int* __restrict__ t4,
    float* __restrict__ acc) {
  float term = 0.f, np = 0.f;
  for (int idx = blockIdx.x * 256 + threadIdx.x; idx < kFocalElems;
       idx += gridDim.x * 256) {
    const int n = idx / 80;       // cell index in concat order
    const int c = idx - n * 80;   // class
    int t;
    const float* crow;
    if (n < 3200) {
      t = t0[n]; crow = c0 + (size_t)n * 80;
    } else if (n < 5792) {
      const int o = n - 3200; t = t1[o]; crow = c1 + (size_t)o * 80;
    } else if (n < 6944) {
      const int o = n - 5792; t = t2[o]; crow = c2 + (size_t)o * 80;
    } else if (n < 7456) {
      const int o = n - 6944; t = t3[o]; crow = c3 + (size_t)o * 80;
    } else {
      const int o = n - 7456; t = t4[o]; crow = c4 + (size_t)o * 80;
    }
    if (t > -1) {
      float pv = crow[c];
      pv = fminf(fmaxf(pv, 1e-4f), 1.f - 1e-4f);
      const bool gm = (c == t);
      const float af = gm ? 0.25f : 0.75f;
      const float pt = gm ? pv : 1.f - pv;
      const float om = 1.f - pt;
      term = fmaf(af * om * om, -__logf(pt), term);
      if (c == 0) np += 1.f;
    }
  }
  term = wave_sum(term);
  np = wave_sum(np);
  __shared__ float st[8];
  const int wid = threadIdx.x >> 6;
  if ((threadIdx.x & 63) == 0) {
    st[wid] = term;
    st[4 + wid] = np;
  }
  __syncthreads();
  if (threadIdx.x == 0) {
    unsafeAtomicAdd(&acc[480], st[0] + st[1] + st[2] + st[3]);
    unsafeAtomicAdd(&acc[481], st[4] + st[5] + st[6] + st[7]);
  }
}

__global__ void zero_kernel(float* __restrict__ acc) {
  const int i = blockIdx.x * 256 + threadIdx.x;
  if (i < 482) acc[i] = 0.f;
}

__global__ __launch_bounds__(64) void finalize_kernel(
    const float* __restrict__ acc, float* __restrict__ out) {
  const int tid = threadIdx.x;
  float s = 0.f;
#pragma unroll
  for (int rr = 0; rr < 3; ++rr) {
    const int r = tid + rr * 64;
    if (r < 160) {
      const float a = acc[r];
      const float bb = acc[160 + r];
      const float cc = acc[320 + r];
      s += 1.f - 2.f * a / (bb + cc + 1e-4f);
    }
  }
  s = wave_sum(s);
  if (tid == 0) {
    out[0] = 3.0f * (s / 160.f);          // MASK_W * mask_loss
    out[1] = acc[480] / acc[481];         // CLS_W * cls_loss
  }
}

}  // namespace

extern "C" void kernel_launch(void* const* d_in, const int* in_sizes, int n_in,
                              void* d_out, int out_size, void* d_ws,
                              size_t ws_size, hipStream_t stream) {
  const float* mask_out = (const float*)d_in[0];
  const float* k[5];
  const float* cc[5];
  const int* pp[5];
  const int* tt[5];
  for (int i = 0; i < 5; ++i) {
    k[i] = (const float*)d_in[1 + 4 * i];
    cc[i] = (const float*)d_in[2 + 4 * i];
    pp[i] = (const int*)d_in[3 + 4 * i];
    tt[i] = (const int*)d_in[4 + 4 * i];
  }
  const float* mt = (const float*)d_in[21];
  float* acc = (float*)d_ws;
  float* out = (float*)d_out;

  hipLaunchKernelGGL(zero_kernel, dim3(2), dim3(256), 0, stream, acc);
  hipLaunchKernelGGL(solov2_main, dim3(144, 2, 2), dim3(256), 0, stream,
                     mask_out, k[0], k[1], k[2], k[3], k[4], pp[0], pp[1],
                     pp[2], pp[3], pp[4], mt, acc);
  hipLaunchKernelGGL(focal_kernel, dim3(320), dim3(256), 0, stream, cc[0],
                     cc[1], cc[2], cc[3], cc[4], tt[0], tt[1], tt[2], tt[3],
                     tt[4], acc);
  hipLaunchKernelGGL(finalize_kernel, dim3(1), dim3(64), 0, stream, acc, out);
}

// Round 4
// 245.109 us; speedup vs baseline: 3.5272x; 1.8897x over previous
//
#include <hip/hip_runtime.h>

namespace {

constexpr int kHW = 36864;  // 192*192
constexpr int kFocalElems = 7744 * 80;
constexpr int kR = 10;      // pred rows per block

__device__ __forceinline__ float wave_sum(float v) {
#pragma unroll
  for (int off = 32; off; off >>= 1) v += __shfl_xor(v, off, 64);
  return v;
}

// ---------------------------------------------------------------------------
// Main fused kernel. Block = 256 threads; 512 pixels (2/thread, float2 loads)
// x 10 pred rows. Grid = (72 pixel-tiles, 8 row-groups, 2 batches) = 1152
// blocks (4.5/CU). K rows staged in LDS (10 KB); inner loop: uniform
// ds_read_b128 of K broadcast over 2 pixels (amortized), double-buffered
// float2 mask_out loads, 20 fp32 accumulators. waves_per_eu(4) pins VGPR<=128
// (live ~90, no spill) for 4 waves/SIMD. Dice partials block-reduced in LDS,
// then one atomic per row per quantity.
// ---------------------------------------------------------------------------
__global__ __attribute__((amdgpu_flat_work_group_size(256, 256),
                          amdgpu_waves_per_eu(4)))
void solov2_main(
    const float* __restrict__ mask_out,
    const float* __restrict__ k0, const float* __restrict__ k1,
    const float* __restrict__ k2, const float* __restrict__ k3,
    const float* __restrict__ k4,
    const int* __restrict__ q0, const int* __restrict__ q1,
    const int* __restrict__ q2, const int* __restrict__ q3,
    const int* __restrict__ q4,
    const float* __restrict__ mask_targets,
    float* __restrict__ acc) {
  const int b = blockIdx.z;
  const int g = blockIdx.y;  // row group: rows [g*10, g*10+10)
  const int pixbase = blockIdx.x * 512 + threadIdx.x * 2;
  const float* __restrict__ mo = mask_out + (size_t)b * 256 * kHW + pixbase;

  const float* kb[5] = {k0, k1, k2, k3, k4};
  const int* pb[5] = {q0, q1, q2, q3, q4};
  const int bg2[5] = {b * 1600, b * 1296, b * 576, b * 256, b * 144};

  __shared__ float klds[kR][256];
  __shared__ float bred[4][3 * kR];

#pragma unroll
  for (int j = 0; j < kR; ++j) {
    const int grow = g * kR + j;
    const int l = grow >> 4, p = grow & 15;  // uniform per j
    const int pos = pb[l][b * 16 + p];
    klds[j][threadIdx.x] = kb[l][(size_t)(bg2[l] + pos) * 256 + threadIdx.x];
  }
  __syncthreads();

  float2 pa[kR];
#pragma unroll
  for (int i = 0; i < kR; ++i) pa[i] = make_float2(0.f, 0.f);

  float2 ma[8], mb_[8];

#define LOADM(M, E0)                                                        \
  {                                                                         \
    _Pragma("unroll") for (int j = 0; j < 8; ++j)                           \
        M[j] = *(const float2*)&mo[(size_t)((E0) + j) * kHW];               \
  }

#define KROWS(M, E0)                                                        \
  {                                                                         \
    _Pragma("unroll") for (int rr = 0; rr < kR; ++rr) {                     \
      const float4 ka = *(const float4*)&klds[rr][(E0)];                    \
      const float4 kc = *(const float4*)&klds[rr][(E0) + 4];                \
      const float kk[8] = {ka.x, ka.y, ka.z, ka.w,                          \
                           kc.x, kc.y, kc.z, kc.w};                         \
      _Pragma("unroll") for (int j = 0; j < 8; ++j) {                       \
        pa[rr].x = fmaf(kk[j], M[j].x, pa[rr].x);                           \
        pa[rr].y = fmaf(kk[j], M[j].y, pa[rr].y);                           \
      }                                                                     \
    }                                                                       \
  }

  // Double-buffered e-loop: prefetch next 8 channels during 160 pk-FMAs.
  LOADM(ma, 0);
  for (int e0 = 0; e0 < 256; e0 += 16) {
    LOADM(mb_, e0 + 8);
    KROWS(ma, e0);
    if (e0 + 16 < 256) LOADM(ma, e0 + 16);
    KROWS(mb_, e0 + 8);
  }
#undef LOADM
#undef KROWS

  // Dice epilogue: per-wave shuffle reduce, block reduce in LDS, one atomic
  // per (row, quantity). Global flat row r = l*32 + b*16 + p pairs with
  // mask_targets flat row r (reference's level-major/image-major pairing
  // collapses to identical flat indexing).
  const int lane = threadIdx.x & 63;
  const int wave = threadIdx.x >> 6;
#pragma unroll
  for (int rr = 0; rr < kR; ++rr) {
    const int grow = g * kR + rr;
    const int l = grow >> 4, p = grow & 15;
    const int r = l * 32 + b * 16 + p;
    const float mp0 = 1.f / (1.f + __expf(-pa[rr].x));
    const float mp1 = 1.f / (1.f + __expf(-pa[rr].y));
    const float2 mt = *(const float2*)&mask_targets[(size_t)r * kHW + pixbase];
    const float av = wave_sum(fmaf(mp0, mt.x, mp1 * mt.y));
    const float bv = wave_sum(fmaf(mp0, mp0, mp1 * mp1));
    const float cv = wave_sum(mt.x + mt.y);  // binary targets: mt*mt == mt
    if (lane == 0) {
      bred[wave][rr] = av;
      bred[wave][kR + rr] = bv;
      bred[wave][2 * kR + rr] = cv;
    }
  }
  __syncthreads();
  if (threadIdx.x < 3 * kR) {
    const int q = threadIdx.x / kR;
    const int rr = threadIdx.x - q * kR;
    const int grow = g * kR + rr;
    const int l = grow >> 4, p = grow & 15;
    const int r = l * 32 + b * 16 + p;
    const float s = bred[0][threadIdx.x] + bred[1][threadIdx.x] +
                    bred[2][threadIdx.x] + bred[3][threadIdx.x];
    unsafeAtomicAdd(&acc[q * 160 + r], s);
  }
}

// ---------------------------------------------------------------------------
// Focal loss over concatenated grid cells. N = 7744 cells x C = 80 classes.
// ---------------------------------------------------------------------------
__global__ __launch_bounds__(256) void focal_kernel(
    const float* __restrict__ c0, const float* __restrict__ c1,
    const float* __restrict__ c2, const float* __restrict__ c3,
    const float* __restrict__ c4,
    const int* __restrict__ t0, const int* __restrict__ t1,
    const int* __restrict__ t2, const int* __restrict__ t3,
    const int* __restrict__ t4,
    float* __restrict__ acc) {
  float term = 0.f, np = 0.f;
  for (int idx = blockIdx.x * 256 + threadIdx.x; idx < kFocalElems;
       idx += gridDim.x * 256) {
    const int n = idx / 80;       // cell index in concat order
    const int c = idx - n * 80;   // class
    int t;
    const float* crow;
    if (n < 3200) {
      t = t0[n]; crow = c0 + (size_t)n * 80;
    } else if (n < 5792) {
      const int o = n - 3200; t = t1[o]; crow = c1 + (size_t)o * 80;
    } else if (n < 6944) {
      const int o = n - 5792; t = t2[o]; crow = c2 + (size_t)o * 80;
    } else if (n < 7456) {
      const int o = n - 6944; t = t3[o]; crow = c3 + (size_t)o * 80;
    } else {
      const int o = n - 7456; t = t4[o]; crow = c4 + (size_t)o * 80;
    }
    if (t > -1) {
      float pv = crow[c];
      pv = fminf(fmaxf(pv, 1e-4f), 1.f - 1e-4f);
      const bool gm = (c == t);
      const float af = gm ? 0.25f : 0.75f;
      const float pt = gm ? pv : 1.f - pv;
      const float om = 1.f - pt;
      term = fmaf(af * om * om, -__logf(pt), term);
      if (c == 0) np += 1.f;
    }
  }
  term = wave_sum(term);
  np = wave_sum(np);
  __shared__ float st[8];
  const int wid = threadIdx.x >> 6;
  if ((threadIdx.x & 63) == 0) {
    st[wid] = term;
    st[4 + wid] = np;
  }
  __syncthreads();
  if (threadIdx.x == 0) {
    unsafeAtomicAdd(&acc[480], st[0] + st[1] + st[2] + st[3]);
    unsafeAtomicAdd(&acc[481], st[4] + st[5] + st[6] + st[7]);
  }
}

__global__ void zero_kernel(float* __restrict__ acc) {
  const int i = blockIdx.x * 256 + threadIdx.x;
  if (i < 482) acc[i] = 0.f;
}

__global__ __launch_bounds__(64) void finalize_kernel(
    const float* __restrict__ acc, float* __restrict__ out) {
  const int tid = threadIdx.x;
  float s = 0.f;
#pragma unroll
  for (int rr = 0; rr < 3; ++rr) {
    const int r = tid + rr * 64;
    if (r < 160) {
      const float a = acc[r];
      const float bb = acc[160 + r];
      const float cc = acc[320 + r];
      s += 1.f - 2.f * a / (bb + cc + 1e-4f);
    }
  }
  s = wave_sum(s);
  if (tid == 0) {
    out[0] = 3.0f * (s / 160.f);          // MASK_W * mask_loss
    out[1] = acc[480] / acc[481];         // CLS_W * cls_loss
  }
}

}  // namespace

extern "C" void kernel_launch(void* const* d_in, const int* in_sizes, int n_in,
                              void* d_out, int out_size, void* d_ws,
                              size_t ws_size, hipStream_t stream) {
  const float* mask_out = (const float*)d_in[0];
  const float* k[5];
  const float* cc[5];
  const int* pp[5];
  const int* tt[5];
  for (int i = 0; i < 5; ++i) {
    k[i] = (const float*)d_in[1 + 4 * i];
    cc[i] = (const float*)d_in[2 + 4 * i];
    pp[i] = (const int*)d_in[3 + 4 * i];
    tt[i] = (const int*)d_in[4 + 4 * i];
  }
  const float* mt = (const float*)d_in[21];
  float* acc = (float*)d_ws;
  float* out = (float*)d_out;

  hipLaunchKernelGGL(zero_kernel, dim3(2), dim3(256), 0, stream, acc);
  hipLaunchKernelGGL(solov2_main, dim3(72, 8, 2), dim3(256), 0, stream,
                     mask_out, k[0], k[1], k[2], k[3], k[4], pp[0], pp[1],
                     pp[2], pp[3], pp[4], mt, acc);
  hipLaunchKernelGGL(focal_kernel, dim3(320), dim3(256), 0, stream, cc[0],
                     cc[1], cc[2], cc[3], cc[4], tt[0], tt[1], tt[2], tt[3],
                     tt[4], acc);
  hipLaunchKernelGGL(finalize_kernel, dim3(1), dim3(64), 0, stream, acc, out);
}

// Round 5
// 67.157 us; speedup vs baseline: 12.8733x; 3.6498x over previous
//
#include <hip/hip_runtime.h>
#include <hip/hip_bf16.h>

namespace {

constexpr int kHW = 36864;  // 192*192
constexpr int kFocalElems = 7744 * 80;

typedef __attribute__((ext_vector_type(8))) short bf16x8;
typedef __attribute__((ext_vector_type(4))) float f32x4;

__device__ __forceinline__ unsigned short f2bf(float x) {
  return __builtin_bit_cast(unsigned short, __float2bfloat16(x));
}

__device__ __forceinline__ float wave_sum(float v) {
#pragma unroll
  for (int off = 32; off; off >>= 1) v += __shfl_xor(v, off, 64);
  return v;
}

// ---------------------------------------------------------------------------
// MFMA main kernel. Block = 256 thr (4 waves) handles 128 pixels x all 80
// pred rows; grid = (288 pixel-tiles, 2 batches). K rows staged once in LDS
// as bf16 [80][264] (pad -> <=2-way bank alias). Each wave: 32 px (2 N-frags)
// x 5 M-tiles x 8 K-steps of mfma_f32_16x16x32_bf16. B-frags gathered from
// mask_out f32 (coalesced 64B per 16-lane group) + cvt to bf16. Epilogue:
// sigmoid, mt gather, 16-lane shfl row-reduce, LDS block-reduce, one atomic
// per (row, quantity) per block into acc[0..479].
// ---------------------------------------------------------------------------
__global__ __launch_bounds__(256, 2) void solov2_main(
    const float* __restrict__ mask_out,
    const float* __restrict__ k0, const float* __restrict__ k1,
    const float* __restrict__ k2, const float* __restrict__ k3,
    const float* __restrict__ k4,
    const int* __restrict__ q0, const int* __restrict__ q1,
    const int* __restrict__ q2, const int* __restrict__ q3,
    const int* __restrict__ q4,
    const float* __restrict__ mask_targets,
    float* __restrict__ acc) {
  const int b = blockIdx.y;
  const int pixbase = blockIdx.x * 128;
  const int lane = threadIdx.x & 63;
  const int wv = threadIdx.x >> 6;

  const float* kb[5] = {k0, k1, k2, k3, k4};
  const int* pb[5] = {q0, q1, q2, q3, q4};
  const int bg2[5] = {b * 1600, b * 1296, b * 576, b * 256, b * 144};

  __shared__ unsigned short klds[80][264];  // bf16, padded row (528 B)
  __shared__ float bred[4][240];            // per-wave row partials (a,b,c)

  // --- stage gathered K rows as bf16: 2 rows per pass, 128 threads/row ---
#pragma unroll 4
  for (int j0 = 0; j0 < 80; j0 += 2) {
    const int row = j0 + (threadIdx.x >> 7);
    const int ch = (threadIdx.x & 127) * 2;
    const int l = row >> 4, p = row & 15;
    const int pos = pb[l][b * 16 + p];
    const float2 kv =
        *(const float2*)(kb[l] + (size_t)(bg2[l] + pos) * 256 + ch);
    *(unsigned int*)&klds[row][ch] =
        (unsigned int)f2bf(kv.x) | ((unsigned int)f2bf(kv.y) << 16);
  }
  __syncthreads();

  // --- MFMA K-loop ---
  const int hi8 = (lane >> 4) * 8;       // k sub-offset for this lane group
  const int pxl = pixbase + wv * 32 + (lane & 15);  // nt=0 pixel
  const float* __restrict__ mop =
      mask_out + (size_t)b * 256 * kHW + (size_t)hi8 * kHW + pxl;

  f32x4 acc5[5][2];
#pragma unroll
  for (int mt = 0; mt < 5; ++mt)
#pragma unroll
    for (int nt = 0; nt < 2; ++nt) acc5[mt][nt] = (f32x4){0.f, 0.f, 0.f, 0.f};

#pragma unroll 2
  for (int ks = 0; ks < 8; ++ks) {
    float fb0[8], fb1[8];
#pragma unroll
    for (int j = 0; j < 8; ++j) {
      const size_t off = (size_t)(ks * 32 + j) * kHW;
      fb0[j] = mop[off];
      fb1[j] = mop[off + 16];
    }
    bf16x8 b0, b1;
#pragma unroll
    for (int j = 0; j < 8; ++j) {
      b0[j] = (short)f2bf(fb0[j]);
      b1[j] = (short)f2bf(fb1[j]);
    }
#pragma unroll
    for (int mt = 0; mt < 5; ++mt) {
      const bf16x8 a =
          *(const bf16x8*)&klds[mt * 16 + (lane & 15)][ks * 32 + hi8];
      acc5[mt][0] =
          __builtin_amdgcn_mfma_f32_16x16x32_bf16(a, b0, acc5[mt][0], 0, 0, 0);
      acc5[mt][1] =
          __builtin_amdgcn_mfma_f32_16x16x32_bf16(a, b1, acc5[mt][1], 0, 0, 0);
    }
  }

  // --- dice epilogue ---
  // D layout (m89): col = lane&15 (pixel), row = (lane>>4)*4 + reg.
  // Global flat row r = (row80>>4)*32 + b*16 + (row80&15); pairs with
  // mask_targets flat row r (reference's level/image-major pairing collapses).
  const float* __restrict__ mtb = mask_targets;
#pragma unroll
  for (int mt = 0; mt < 5; ++mt) {
#pragma unroll
    for (int j = 0; j < 4; ++j) {
      const int row80 = mt * 16 + (lane >> 4) * 4 + j;
      const int r = (row80 >> 4) * 32 + b * 16 + (row80 & 15);
      const float x0 = acc5[mt][0][j];
      const float x1 = acc5[mt][1][j];
      const float mp0 = 1.f / (1.f + __expf(-x0));
      const float mp1 = 1.f / (1.f + __expf(-x1));
      const size_t base = (size_t)r * kHW + pxl;
      const float t0v = mtb[base];
      const float t1v = mtb[base + 16];
      float av = fmaf(mp0, t0v, mp1 * t1v);
      float bv = fmaf(mp0, mp0, mp1 * mp1);
      float cv = t0v + t1v;  // binary targets: mt*mt == mt
#pragma unroll
      for (int m = 1; m <= 8; m <<= 1) {
        av += __shfl_xor(av, m, 64);
        bv += __shfl_xor(bv, m, 64);
        cv += __shfl_xor(cv, m, 64);
      }
      if ((lane & 15) == 0) {
        bred[wv][row80] = av;
        bred[wv][80 + row80] = bv;
        bred[wv][160 + row80] = cv;
      }
    }
  }
  __syncthreads();
  if (threadIdx.x < 240) {
    const int q = threadIdx.x / 80;
    const int row80 = threadIdx.x - q * 80;
    const int r = (row80 >> 4) * 32 + b * 16 + (row80 & 15);
    const float s = bred[0][threadIdx.x] + bred[1][threadIdx.x] +
                    bred[2][threadIdx.x] + bred[3][threadIdx.x];
    unsafeAtomicAdd(&acc[q * 160 + r], s);
  }
}

// ---------------------------------------------------------------------------
// Focal loss over concatenated grid cells. N = 7744 cells x C = 80 classes.
// ---------------------------------------------------------------------------
__global__ __launch_bounds__(256) void focal_kernel(
    const float* __restrict__ c0, const float* __restrict__ c1,
    const float* __restrict__ c2, const float* __restrict__ c3,
    const float* __restrict__ c4,
    const int* __restrict__ t0, const int* __restrict__ t1,
    const int* __restrict__ t2, const int* __restrict__ t3,
    const int* __restrict__ t4,
    float* __restrict__ acc) {
  float term = 0.f, np = 0.f;
  for (int idx = blockIdx.x * 256 + threadIdx.x; idx < kFocalElems;
       idx += gridDim.x * 256) {
    const int n = idx / 80;       // cell index in concat order
    const int c = idx - n * 80;   // class
    int t;
    const float* crow;
    if (n < 3200) {
      t = t0[n]; crow = c0 + (size_t)n * 80;
    } else if (n < 5792) {
      const int o = n - 3200; t = t1[o]; crow = c1 + (size_t)o * 80;
    } else if (n < 6944) {
      const int o = n - 5792; t = t2[o]; crow = c2 + (size_t)o * 80;
    } else if (n < 7456) {
      const int o = n - 6944; t = t3[o]; crow = c3 + (size_t)o * 80;
    } else {
      const int o = n - 7456; t = t4[o]; crow = c4 + (size_t)o * 80;
    }
    if (t > -1) {
      float pv = crow[c];
      pv = fminf(fmaxf(pv, 1e-4f), 1.f - 1e-4f);
      const bool gm = (c == t);
      const float af = gm ? 0.25f : 0.75f;
      const float pt = gm ? pv : 1.f - pv;
      const float om = 1.f - pt;
      term = fmaf(af * om * om, -__logf(pt), term);
      if (c == 0) np += 1.f;
    }
  }
  term = wave_sum(term);
  np = wave_sum(np);
  __shared__ float st[8];
  const int wid = threadIdx.x >> 6;
  if ((threadIdx.x & 63) == 0) {
    st[wid] = term;
    st[4 + wid] = np;
  }
  __syncthreads();
  if (threadIdx.x == 0) {
    unsafeAtomicAdd(&acc[480], st[0] + st[1] + st[2] + st[3]);
    unsafeAtomicAdd(&acc[481], st[4] + st[5] + st[6] + st[7]);
  }
}

__global__ void zero_kernel(float* __restrict__ acc) {
  const int i = blockIdx.x * 256 + threadIdx.x;
  if (i < 482) acc[i] = 0.f;
}

__global__ __launch_bounds__(64) void finalize_kernel(
    const float* __restrict__ acc, float* __restrict__ out) {
  const int tid = threadIdx.x;
  float s = 0.f;
#pragma unroll
  for (int rr = 0; rr < 3; ++rr) {
    const int r = tid + rr * 64;
    if (r < 160) {
      const float a = acc[r];
      const float bb = acc[160 + r];
      const float cc = acc[320 + r];
      s += 1.f - 2.f * a / (bb + cc + 1e-4f);
    }
  }
  s = wave_sum(s);
  if (tid == 0) {
    out[0] = 3.0f * (s / 160.f);          // MASK_W * mask_loss
    out[1] = acc[480] / acc[481];         // CLS_W * cls_loss
  }
}

}  // namespace

extern "C" void kernel_launch(void* const* d_in, const int* in_sizes, int n_in,
                              void* d_out, int out_size, void* d_ws,
                              size_t ws_size, hipStream_t stream) {
  const float* mask_out = (const float*)d_in[0];
  const float* k[5];
  const float* cc[5];
  const int* pp[5];
  const int* tt[5];
  for (int i = 0; i < 5; ++i) {
    k[i] = (const float*)d_in[1 + 4 * i];
    cc[i] = (const float*)d_in[2 + 4 * i];
    pp[i] = (const int*)d_in[3 + 4 * i];
    tt[i] = (const int*)d_in[4 + 4 * i];
  }
  const float* mt = (const float*)d_in[21];
  float* acc = (float*)d_ws;
  float* out = (float*)d_out;

  hipLaunchKernelGGL(zero_kernel, dim3(2), dim3(256), 0, stream, acc);
  hipLaunchKernelGGL(solov2_main, dim3(288, 2), dim3(256), 0, stream,
                     mask_out, k[0], k[1], k[2], k[3], k[4], pp[0], pp[1],
                     pp[2], pp[3], pp[4], mt, acc);
  hipLaunchKernelGGL(focal_kernel, dim3(320), dim3(256), 0, stream, cc[0],
                     cc[1], cc[2], cc[3], cc[4], tt[0], tt[1], tt[2], tt[3],
                     tt[4], acc);
  hipLaunchKernelGGL(finalize_kernel, dim3(1), dim3(64), 0, stream, acc, out);
}